// Round 1
// baseline (1813.419 us; speedup 1.0000x reference)
//
#include <hip/hip_runtime.h>
#include <hip/hip_fp16.h>

#define T_STEPS 256
#define OBS 512      // obs dim = number of independent per-row LSTMs
#define ACT 32
#define HID 1024     // output rows (hidden_dim)
#define PED 128      // pos_em_dim = LSTM hidden size
#define MSG 128      // msg_dim
#define GATES 512    // 4*PED

__device__ __forceinline__ float sigmoidf_fast(float x) {
    return 1.0f / (1.0f + __expf(-x));
}
// stable tanh: no inf/inf NaN for large |x|
__device__ __forceinline__ float tanhf_fast(float x) {
    float ax = fabsf(x);
    float e  = __expf(2.0f * ax);        // e >= 1; inf for large ax -> t = 1
    float t  = 1.0f - 2.0f / (e + 1.0f);
    return copysignf(t, x);
}

// ---------------------------------------------------------------------------
// Kernel 1: per-t precompute: xnorm[t,n] and apre[t,j]
//   xnorm = (obs - shift)/(scale+1e-8)
//   apre[t,j] = b_ih[j] + b_hh[j] + sum_u act[t,u] * W_ih[j, 1+u]
// grid: T blocks x 256 threads
// ---------------------------------------------------------------------------
__global__ void k_pre(const float* __restrict__ obs, const float* __restrict__ act,
                      const float* __restrict__ shift, const float* __restrict__ scale,
                      const float* __restrict__ W_ih, const float* __restrict__ b_ih,
                      const float* __restrict__ b_hh,
                      float* __restrict__ xnorm, float* __restrict__ apre) {
    int t = blockIdx.x;
    int tid = threadIdx.x;
    __shared__ float a_s[ACT];
    if (tid < ACT) a_s[tid] = act[t * ACT + tid];
    __syncthreads();
    for (int n = tid; n < OBS; n += 256) {
        xnorm[t * OBS + n] = (obs[t * OBS + n] - shift[n]) / (scale[n] + 1e-8f);
    }
    for (int j = tid; j < GATES; j += 256) {
        float acc = b_ih[j] + b_hh[j];
        const float* wr = W_ih + j * 33 + 1;
#pragma unroll
        for (int u = 0; u < ACT; ++u) acc = fmaf(a_s[u], wr[u], acc);
        apre[t * GATES + j] = acc;
    }
}

// ---------------------------------------------------------------------------
// Kernel 2: q[m,d] = sum_p pe[m,p] * Wq[d,p] + bq[d]
// grid: HID blocks x 128 threads
// ---------------------------------------------------------------------------
__global__ void k_qproj(const float* __restrict__ pe, const float* __restrict__ Wq,
                        const float* __restrict__ bq, float* __restrict__ q) {
    int m = blockIdx.x;
    int d = threadIdx.x;  // 0..127
    __shared__ float pe_s[PED];
    pe_s[d] = pe[m * PED + d];
    __syncthreads();
    const float* wr = Wq + d * PED;
    float a0 = bq[d], a1 = 0.f, a2 = 0.f, a3 = 0.f;
#pragma unroll
    for (int p = 0; p < PED; p += 4) {
        a0 = fmaf(pe_s[p + 0], wr[p + 0], a0);
        a1 = fmaf(pe_s[p + 1], wr[p + 1], a1);
        a2 = fmaf(pe_s[p + 2], wr[p + 2], a2);
        a3 = fmaf(pe_s[p + 3], wr[p + 3], a3);
    }
    q[m * PED + d] = (a0 + a1) + (a2 + a3);
}

// ---------------------------------------------------------------------------
// Kernel 3: LSTM scan. 256 blocks, each owns 2 rows (n0, n0+1) for all T.
// Thread tid owns gate outputs j0=tid, j1=tid+256 with W_hh rows in VGPRs
// (weight-stationary across all 256 steps); also owns k output jk=tid&127 for
// row r=tid>>7 with Wk row in VGPRs. h broadcast via LDS float4 reads.
// Writes K[t, n, d] (T x OBS x MSG) to workspace.
// ---------------------------------------------------------------------------
__global__ __launch_bounds__(256, 1)
void k_lstm(const float* __restrict__ xnorm, const float* __restrict__ apre,
            const float* __restrict__ W_ih, const float* __restrict__ W_hh,
            const float* __restrict__ Wk, const float* __restrict__ bk,
            float* __restrict__ K) {
    const int tid = threadIdx.x;
    const int n0 = blockIdx.x * 2;
    const int j0 = tid, j1 = tid + 256;
    const int r_e = tid >> 7, p_e = tid & 127;   // epilogue + k-phase assignment
    const int jk = tid & 127;

    // ---- weight preload (stationary in VGPRs for all 256 steps) ----
    float4 w0[32], w1[32], wk[32];
    const float4* Wr0 = (const float4*)(W_hh + j0 * PED);
    const float4* Wr1 = (const float4*)(W_hh + j1 * PED);
    const float4* Wkr = (const float4*)(Wk + jk * PED);
#pragma unroll
    for (int i = 0; i < 32; ++i) { w0[i] = Wr0[i]; w1[i] = Wr1[i]; wk[i] = Wkr[i]; }
    const float wih0_0 = W_ih[j0 * 33];
    const float wih0_1 = W_ih[j1 * 33];
    const float bk_r = bk[jk];

    __shared__ float h_s[2][PED];
    __shared__ float g_s[2][GATES];
    if (tid < 128) { h_s[0][tid] = 0.f; h_s[1][tid] = 0.f; }
    float c_reg = 0.f;   // c[r_e][p_e] lives in this thread
    __syncthreads();

    for (int t = 0; t < T_STEPS; ++t) {
        // ---- phase 1: gates for both rows (reads h_s of previous step) ----
        const float x0 = xnorm[t * OBS + n0];
        const float x1 = xnorm[t * OBS + n0 + 1];
        const float ap0 = apre[t * GATES + j0];
        const float ap1 = apre[t * GATES + j1];
        float acc00 = fmaf(x0, wih0_0, ap0);   // row0, gate j0
        float acc01 = fmaf(x0, wih0_1, ap1);   // row0, gate j1
        float acc10 = fmaf(x1, wih0_0, ap0);   // row1, gate j0
        float acc11 = fmaf(x1, wih0_1, ap1);   // row1, gate j1
        const float4* h40 = (const float4*)h_s[0];
        const float4* h41 = (const float4*)h_s[1];
#pragma unroll
        for (int i = 0; i < 32; ++i) {
            float4 hv0 = h40[i];
            float4 hv1 = h41[i];
            acc00 = fmaf(hv0.x, w0[i].x, acc00);
            acc01 = fmaf(hv0.x, w1[i].x, acc01);
            acc10 = fmaf(hv1.x, w0[i].x, acc10);
            acc11 = fmaf(hv1.x, w1[i].x, acc11);
            acc00 = fmaf(hv0.y, w0[i].y, acc00);
            acc01 = fmaf(hv0.y, w1[i].y, acc01);
            acc10 = fmaf(hv1.y, w0[i].y, acc10);
            acc11 = fmaf(hv1.y, w1[i].y, acc11);
            acc00 = fmaf(hv0.z, w0[i].z, acc00);
            acc01 = fmaf(hv0.z, w1[i].z, acc01);
            acc10 = fmaf(hv1.z, w0[i].z, acc10);
            acc11 = fmaf(hv1.z, w1[i].z, acc11);
            acc00 = fmaf(hv0.w, w0[i].w, acc00);
            acc01 = fmaf(hv0.w, w1[i].w, acc01);
            acc10 = fmaf(hv1.w, w0[i].w, acc10);
            acc11 = fmaf(hv1.w, w1[i].w, acc11);
        }
        g_s[0][j0] = acc00; g_s[0][j1] = acc01;
        g_s[1][j0] = acc10; g_s[1][j1] = acc11;
        __syncthreads();

        // ---- phase 2: LSTM cell update; thread -> (r_e, p_e) component ----
        {
            float gi = g_s[r_e][p_e];
            float gf = g_s[r_e][128 + p_e];
            float gg = g_s[r_e][256 + p_e];
            float go = g_s[r_e][384 + p_e];
            float cn = sigmoidf_fast(gf) * c_reg + sigmoidf_fast(gi) * tanhf_fast(gg);
            c_reg = cn;
            h_s[r_e][p_e] = sigmoidf_fast(go) * tanhf_fast(cn);
        }
        __syncthreads();

        // ---- phase 3: k = h' @ Wk^T + bk for this thread's (r_e, jk) ----
        {
            const float4* h4 = (const float4*)h_s[r_e];
            float k0 = bk_r, k1 = 0.f, k2 = 0.f, k3 = 0.f;
#pragma unroll
            for (int i = 0; i < 32; ++i) {
                float4 hv = h4[i];
                k0 = fmaf(hv.x, wk[i].x, k0);
                k1 = fmaf(hv.y, wk[i].y, k1);
                k2 = fmaf(hv.z, wk[i].z, k2);
                k3 = fmaf(hv.w, wk[i].w, k3);
            }
            K[(size_t)t * (OBS * MSG) + (size_t)(n0 + r_e) * MSG + jk] = (k0 + k1) + (k2 + k3);
        }
        // next phase-1 only reads h_s (written pre-barrier) and writes g_s
        // (last read pre-barrier of phase 2... separated by the phase-2 barrier
        // of THIS step plus the phase-1 barrier of the NEXT step)
        __syncthreads();
    }
}

// ---------------------------------------------------------------------------
// Kernel 4: attention readout, fully parallel over (t, m).
//   out[t,m] = tanh( sum_n tanh( (q_m . k_{t,n}) * inv ) * s[t,n] )
// grid: T*4 blocks x 256 threads; thread owns m, q_m in VGPRs; K staged in LDS
// in 64-row chunks.
// ---------------------------------------------------------------------------
__global__ __launch_bounds__(256, 1)
void k_attn(const float* __restrict__ q, const float* __restrict__ K,
            const float* __restrict__ xnorm, float* __restrict__ out) {
    const int t = blockIdx.x >> 2;
    const int mt = blockIdx.x & 3;
    const int tid = threadIdx.x;
    const int m = mt * 256 + tid;
    const float inv = 0.08838834764831845f;  // 1/sqrt(128)

    float4 qr[32];
    const float4* q4 = (const float4*)(q + (size_t)m * PED);
#pragma unroll
    for (int i = 0; i < 32; ++i) qr[i] = q4[i];

    __shared__ float k_s[64 * MSG];
    __shared__ float s_s[64];
    float acc = 0.f;

    for (int nc = 0; nc < OBS; nc += 64) {
        __syncthreads();
        // stage K[t, nc..nc+63, :] -> LDS (2048 float4, 8 per thread), coalesced
        const float4* src = (const float4*)(K + (size_t)t * OBS * MSG + (size_t)nc * MSG);
        float4* dst = (float4*)k_s;
#pragma unroll
        for (int i = 0; i < 8; ++i) dst[tid + 256 * i] = src[tid + 256 * i];
        if (tid < 64) s_s[tid] = xnorm[t * OBS + nc + tid];
        __syncthreads();

        for (int n = 0; n < 64; ++n) {
            const float4* k4 = (const float4*)(k_s + n * MSG);
            float s0 = 0.f, s1 = 0.f, s2 = 0.f, s3 = 0.f;
#pragma unroll
            for (int i = 0; i < 32; ++i) {
                float4 kv = k4[i];
                s0 = fmaf(qr[i].x, kv.x, s0);
                s1 = fmaf(qr[i].y, kv.y, s1);
                s2 = fmaf(qr[i].z, kv.z, s2);
                s3 = fmaf(qr[i].w, kv.w, s3);
            }
            float sc = (s0 + s1) + (s2 + s3);
            float w = tanhf_fast(sc * inv);
            acc = fmaf(w, s_s[n], acc);
        }
    }
    out[(size_t)t * HID + m] = tanhf_fast(acc);
}

// ---------------------------------------------------------------------------
extern "C" void kernel_launch(void* const* d_in, const int* in_sizes, int n_in,
                              void* d_out, int out_size, void* d_ws, size_t ws_size,
                              hipStream_t stream) {
    const float* obs      = (const float*)d_in[0];   // (256,512)
    const float* prev_act = (const float*)d_in[1];   // (256,32)
    const float* in_shift = (const float*)d_in[2];   // (512,)
    const float* in_scale = (const float*)d_in[3];   // (512,)
    const float* pos_emb  = (const float*)d_in[4];   // (1024,128)
    const float* W_ih     = (const float*)d_in[5];   // (512,33)
    const float* b_ih     = (const float*)d_in[6];   // (512,)
    const float* W_hh     = (const float*)d_in[7];   // (512,128)
    const float* b_hh     = (const float*)d_in[8];   // (512,)
    const float* Wq       = (const float*)d_in[9];   // (128,128)
    const float* bq       = (const float*)d_in[10];  // (128,)
    const float* Wk       = (const float*)d_in[11];  // (128,128)
    const float* bk       = (const float*)d_in[12];  // (128,)
    float* outp = (float*)d_out;                     // (256,1024)

    // workspace layout (floats):
    //   q:     HID*PED       = 131072
    //   xnorm: T*OBS         = 131072
    //   apre:  T*GATES       = 131072
    //   K:     T*OBS*MSG     = 16777216   (64 MB)
    float* ws    = (float*)d_ws;
    float* qbuf  = ws;
    float* xnorm = ws + 131072;
    float* apre  = ws + 262144;
    float* Kbuf  = ws + 393216;

    k_pre<<<T_STEPS, 256, 0, stream>>>(obs, prev_act, in_shift, in_scale,
                                       W_ih, b_ih, b_hh, xnorm, apre);
    k_qproj<<<HID, 128, 0, stream>>>(pos_emb, Wq, bq, qbuf);
    k_lstm<<<OBS / 2, 256, 0, stream>>>(xnorm, apre, W_ih, W_hh, Wk, bk, Kbuf);
    k_attn<<<T_STEPS * 4, 256, 0, stream>>>(qbuf, Kbuf, xnorm, outp);
}

// Round 2
// 475.632 us; speedup vs baseline: 3.8126x; 3.8126x over previous
//
#include <hip/hip_runtime.h>
#include <hip/hip_fp16.h>

#define T_STEPS 256
#define OBS 512      // obs dim = number of independent per-row LSTMs
#define ACT 32
#define HID 1024     // output rows (hidden_dim)
#define PED 128      // pos_em_dim = LSTM hidden size
#define MSG 128      // msg_dim
#define GATES 512    // 4*PED

typedef _Float16 half2v __attribute__((ext_vector_type(2)));
typedef _Float16 half8  __attribute__((ext_vector_type(8)));
typedef float    floatx4 __attribute__((ext_vector_type(4)));

union Half8U { half8 v8; half2v v2[4]; };

__device__ __forceinline__ float fast_exp2(float x) { return __builtin_amdgcn_exp2f(x); }
__device__ __forceinline__ float fast_rcp(float x)  { return __builtin_amdgcn_rcpf(x); }
// sigmoid(x) = 1/(1+2^(-x*log2e))
__device__ __forceinline__ float sigmoid_f(float x) {
    return fast_rcp(1.0f + fast_exp2(-1.4426950408889634f * x));
}
// tanh(x) = 1 - 2/(2^(2x*log2e)+1)  (valid for both signs, saturates cleanly)
__device__ __forceinline__ float tanh_f(float x) {
    return fmaf(-2.0f, fast_rcp(fast_exp2(2.8853900817779268f * x) + 1.0f), 1.0f);
}

// ---------------------------------------------------------------------------
// Kernel 1: xnorm[t,n] and apre[t,j] precompute (unchanged from R1)
// ---------------------------------------------------------------------------
__global__ void k_pre(const float* __restrict__ obs, const float* __restrict__ act,
                      const float* __restrict__ shift, const float* __restrict__ scale,
                      const float* __restrict__ W_ih, const float* __restrict__ b_ih,
                      const float* __restrict__ b_hh,
                      float* __restrict__ xnorm, float* __restrict__ apre) {
    int t = blockIdx.x;
    int tid = threadIdx.x;
    __shared__ float a_s[ACT];
    if (tid < ACT) a_s[tid] = act[t * ACT + tid];
    __syncthreads();
    for (int n = tid; n < OBS; n += 256) {
        xnorm[t * OBS + n] = (obs[t * OBS + n] - shift[n]) / (scale[n] + 1e-8f);
    }
    for (int j = tid; j < GATES; j += 256) {
        float acc = b_ih[j] + b_hh[j];
        const float* wr = W_ih + j * 33 + 1;
#pragma unroll
        for (int u = 0; u < ACT; ++u) acc = fmaf(a_s[u], wr[u], acc);
        apre[t * GATES + j] = acc;
    }
}

// ---------------------------------------------------------------------------
// Kernel 2: q_h[m,d] = fp16( (pe[m]·Wq[d] + bq[d]) * 2*log2e/sqrt(128) )
// scale folded so attention epilogue is tanh(s*inv) = 1-2/(exp2(S')+1)
// ---------------------------------------------------------------------------
#define QSCALE 0.2550348805576823f

__global__ void k_qproj(const float* __restrict__ pe, const float* __restrict__ Wq,
                        const float* __restrict__ bq, _Float16* __restrict__ qh) {
    int m = blockIdx.x;
    int d = threadIdx.x;  // 0..127
    __shared__ float pe_s[PED];
    pe_s[d] = pe[m * PED + d];
    __syncthreads();
    const float* wr = Wq + d * PED;
    float a0 = bq[d], a1 = 0.f, a2 = 0.f, a3 = 0.f;
#pragma unroll
    for (int p = 0; p < PED; p += 4) {
        a0 = fmaf(pe_s[p + 0], wr[p + 0], a0);
        a1 = fmaf(pe_s[p + 1], wr[p + 1], a1);
        a2 = fmaf(pe_s[p + 2], wr[p + 2], a2);
        a3 = fmaf(pe_s[p + 3], wr[p + 3], a3);
    }
    qh[m * PED + d] = (_Float16)(((a0 + a1) + (a2 + a3)) * QSCALE);
}

// ---------------------------------------------------------------------------
// Kernel 3: LSTM scan, 512 blocks x 256 threads (1 row per block, 2 blocks/CU).
// fp16 weights in VGPRs + v_dot2_f32_f16. Thread tid computes gates tid and
// tid+256. Phase3: 2 threads per k-output (half-dot each) combined via LDS.
// K written as fp16.
// ---------------------------------------------------------------------------
__global__ __launch_bounds__(256, 2)
void k_lstm(const float* __restrict__ xnorm, const float* __restrict__ apre,
            const float* __restrict__ W_ih, const float* __restrict__ W_hh,
            const float* __restrict__ Wk, const float* __restrict__ bk,
            _Float16* __restrict__ K16) {
    const int tid = threadIdx.x;
    const int n = blockIdx.x;                 // row this block owns
    const int j0 = tid, j1 = tid + 256;
    const int jk = tid & 127, hf = tid >> 7;  // phase-3 half-dot assignment

    // ---- fp16 weight preload (stationary in VGPRs) ----
    half2v wh0[64], wh1[64], wk[32];
    {
        const float2* p0 = (const float2*)(W_hh + (size_t)j0 * PED);
        const float2* p1 = (const float2*)(W_hh + (size_t)j1 * PED);
#pragma unroll
        for (int i = 0; i < 64; ++i) {
            float2 f0 = p0[i], f1 = p1[i];
            wh0[i] = (half2v){(_Float16)f0.x, (_Float16)f0.y};
            wh1[i] = (half2v){(_Float16)f1.x, (_Float16)f1.y};
        }
        const float2* pk = (const float2*)(Wk + (size_t)jk * PED + hf * 64);
#pragma unroll
        for (int i = 0; i < 32; ++i) {
            float2 f = pk[i];
            wk[i] = (half2v){(_Float16)f.x, (_Float16)f.y};
        }
    }
    const float wih00 = W_ih[j0 * 33];
    const float wih01 = W_ih[j1 * 33];
    const float bk_s = (tid < 128) ? bk[tid] : 0.f;

    __shared__ half8 h8_s[16];                // h state, fp16, 128 values
    __shared__ float g_s[GATES];
    __shared__ float kpart[256];
    __shared__ float x_s[T_STEPS];

    x_s[tid] = xnorm[tid * OBS + n];          // preload this row's x for all t
    if (tid < 128) ((_Float16*)h8_s)[tid] = (_Float16)0.f;
    float c_reg = 0.f;                        // c[p] for p=tid (tid<128)
    __syncthreads();

#pragma unroll 1
    for (int t = 0; t < T_STEPS; ++t) {
        // ---- phase 1: two gate dots over h (fp16 dot2, fp32 acc) ----
        const float x = x_s[t];
        float acc0 = fmaf(x, wih00, apre[t * GATES + j0]);
        float acc1 = fmaf(x, wih01, apre[t * GATES + j1]);
#pragma unroll
        for (int i = 0; i < 16; ++i) {
            Half8U hv; hv.v8 = h8_s[i];
#pragma unroll
            for (int k = 0; k < 4; ++k) {
                acc0 = __builtin_amdgcn_fdot2(hv.v2[k], wh0[i * 4 + k], acc0, false);
                acc1 = __builtin_amdgcn_fdot2(hv.v2[k], wh1[i * 4 + k], acc1, false);
            }
        }
        g_s[j0] = acc0;
        g_s[j1] = acc1;
        __syncthreads();

        // ---- phase 2: cell update (threads 0..127 = waves 0,1) ----
        if (tid < 128) {
            float gi = g_s[tid];
            float gf = g_s[tid + 128];
            float gg = g_s[tid + 256];
            float go = g_s[tid + 384];
            float cn = sigmoid_f(gf) * c_reg + sigmoid_f(gi) * tanh_f(gg);
            c_reg = cn;
            float h = sigmoid_f(go) * tanh_f(cn);
            ((_Float16*)h8_s)[tid] = (_Float16)h;
        }
        __syncthreads();

        // ---- phase 3: k = h'·Wk^T (half-dot per thread) ----
        {
            float p = 0.f;
#pragma unroll
            for (int i = 0; i < 8; ++i) {
                Half8U hv; hv.v8 = h8_s[hf * 8 + i];
#pragma unroll
                for (int k = 0; k < 4; ++k)
                    p = __builtin_amdgcn_fdot2(hv.v2[k], wk[i * 4 + k], p, false);
            }
            kpart[tid] = p;
        }
        __syncthreads();

        if (tid < 128) {
            float kv = kpart[tid] + kpart[tid + 128] + bk_s;
            K16[(size_t)t * (OBS * MSG) + (size_t)n * MSG + tid] = (_Float16)kv;
        }
        // next phase-1 write of g_s is fenced by the phase-2 barrier path:
        // all threads must pass the next iteration's post-phase-1 barrier
        // only after every thread has finished this combine (3 barriers/step).
    }
}

// ---------------------------------------------------------------------------
// Kernel 4: attention via fp16 MFMA.
//   S'[m,n] = qh[m]·k[t,n]  (scale prefolded), w = 1-2/(exp2(S')+1)
//   out[t,m] = tanh( sum_n w*s[t,n] )
// grid: T*4 blocks (t, m-quarter of 256), 256 threads = 4 waves; wave owns
// 64 m rows (4 MFMA m-tiles). K_t staged in LDS in 64-row chunks.
// ---------------------------------------------------------------------------
__global__ __launch_bounds__(256, 2)
void k_attn(const _Float16* __restrict__ qh, const _Float16* __restrict__ K16,
            const float* __restrict__ xnorm, float* __restrict__ outp) {
    const int t = blockIdx.x >> 2;
    const int mq = blockIdx.x & 3;
    const int tid = threadIdx.x;
    const int lane = tid & 63;
    const int wave = tid >> 6;
    const int l15 = lane & 15;
    const int quad = lane >> 4;

    // ---- A-fragments: qh rows for this wave's 64 m, held in VGPRs ----
    // A[m=lane&15][k=quad*8+j]; 4 m-tiles x 4 k-chunks
    half8 afrag[4][4];
    {
        const int m0 = mq * 256 + wave * 64;
#pragma unroll
        for (int mt = 0; mt < 4; ++mt) {
            const half8* qrow = (const half8*)(qh + (size_t)(m0 + mt * 16 + l15) * PED);
#pragma unroll
            for (int c = 0; c < 4; ++c) afrag[mt][c] = qrow[c * 4 + quad];
        }
    }

    __shared__ half8 kbuf[64 * 16];   // 64 rows x 128 halfs = 16 KB
    __shared__ float s_s[64];

    float outacc[16];
#pragma unroll
    for (int i = 0; i < 16; ++i) outacc[i] = 0.f;

    for (int nc = 0; nc < OBS; nc += 64) {
        __syncthreads();
        // stage K[t, nc..nc+63, :] -> LDS, coalesced half8 loads
        const half8* src = (const half8*)(K16 + (size_t)t * (OBS * MSG) + (size_t)nc * MSG);
#pragma unroll
        for (int it = 0; it < 4; ++it) {
            int f = it * 256 + tid;
            kbuf[f] = src[f];
        }
        if (tid < 64) s_s[tid] = xnorm[t * OBS + nc + tid];
        __syncthreads();

#pragma unroll
        for (int nt = 0; nt < 4; ++nt) {
            // B-frag: B[k=quad*8+j][n=lane&15] = K[n][k] (row-major, same pattern as A)
            half8 bfrag[4];
#pragma unroll
            for (int c = 0; c < 4; ++c)
                bfrag[c] = kbuf[(nt * 16 + l15) * 16 + c * 4 + quad];

            floatx4 acc[4];
#pragma unroll
            for (int mt = 0; mt < 4; ++mt) {
                acc[mt] = (floatx4){0.f, 0.f, 0.f, 0.f};
#pragma unroll
                for (int c = 0; c < 4; ++c)
                    acc[mt] = __builtin_amdgcn_mfma_f32_16x16x32_f16(
                        afrag[mt][c], bfrag[c], acc[mt], 0, 0, 0);
            }

            // epilogue: this lane's column n is fixed; S for m = quad*4+r
            const float s_val = s_s[nt * 16 + l15];
#pragma unroll
            for (int mt = 0; mt < 4; ++mt) {
#pragma unroll
                for (int r = 0; r < 4; ++r) {
                    float e = fast_exp2(acc[mt][r]);       // exp2(2*log2e*S*inv)
                    float w = fmaf(-2.0f, fast_rcp(e + 1.0f), 1.0f);
                    outacc[mt * 4 + r] = fmaf(w, s_val, outacc[mt * 4 + r]);
                }
            }
        }
    }

    // ---- reduce across the 16 lanes sharing each (quad, r) m-row ----
#pragma unroll
    for (int i = 0; i < 16; ++i) {
        float v = outacc[i];
        v += __shfl_xor(v, 1, 16);
        v += __shfl_xor(v, 2, 16);
        v += __shfl_xor(v, 4, 16);
        v += __shfl_xor(v, 8, 16);
        outacc[i] = v;
    }
    if (l15 == 0) {
        const int mbase = mq * 256 + wave * 64 + quad * 4;
#pragma unroll
        for (int mt = 0; mt < 4; ++mt)
#pragma unroll
            for (int r = 0; r < 4; ++r)
                outp[(size_t)t * HID + mbase + mt * 16 + r] = tanh_f(outacc[mt * 4 + r]);
    }
}

// ---------------------------------------------------------------------------
extern "C" void kernel_launch(void* const* d_in, const int* in_sizes, int n_in,
                              void* d_out, int out_size, void* d_ws, size_t ws_size,
                              hipStream_t stream) {
    const float* obs      = (const float*)d_in[0];   // (256,512)
    const float* prev_act = (const float*)d_in[1];   // (256,32)
    const float* in_shift = (const float*)d_in[2];   // (512,)
    const float* in_scale = (const float*)d_in[3];   // (512,)
    const float* pos_emb  = (const float*)d_in[4];   // (1024,128)
    const float* W_ih     = (const float*)d_in[5];   // (512,33)
    const float* b_ih     = (const float*)d_in[6];   // (512,)
    const float* W_hh     = (const float*)d_in[7];   // (512,128)
    const float* b_hh     = (const float*)d_in[8];   // (512,)
    const float* Wq       = (const float*)d_in[9];   // (128,128)
    const float* bq       = (const float*)d_in[10];  // (128,)
    const float* Wk       = (const float*)d_in[11];  // (128,128)
    const float* bk       = (const float*)d_in[12];  // (128,)
    float* outp = (float*)d_out;                     // (256,1024)

    // workspace layout (float offsets):
    //   xnorm: 0       (131072 floats)
    //   apre:  131072  (131072 floats)
    //   qh:    262144  (131072 halfs = 65536 floats)
    //   K16:   327680  (16777216 halfs = 8388608 floats)
    float* ws = (float*)d_ws;
    float* xnorm = ws;
    float* apre  = ws + 131072;
    _Float16* qh  = (_Float16*)(ws + 262144);
    _Float16* K16 = (_Float16*)(ws + 327680);

    k_pre<<<T_STEPS, 256, 0, stream>>>(obs, prev_act, in_shift, in_scale,
                                       W_ih, b_ih, b_hh, xnorm, apre);
    k_qproj<<<HID, 128, 0, stream>>>(pos_emb, Wq, bq, qh);
    k_lstm<<<OBS, 256, 0, stream>>>(xnorm, apre, W_ih, W_hh, Wk, bk, K16);
    k_attn<<<T_STEPS * 4, 256, 0, stream>>>(qh, K16, xnorm, outp);
}

// Round 3
// 427.124 us; speedup vs baseline: 4.2456x; 1.1136x over previous
//
#include <hip/hip_runtime.h>
#include <hip/hip_fp16.h>

#define T_STEPS 256
#define OBS 512      // obs dim = number of independent per-row LSTMs
#define ACT 32
#define HID 1024     // output rows (hidden_dim)
#define PED 128      // pos_em_dim = LSTM hidden size
#define MSG 128      // msg_dim
#define GATES 512    // 4*PED
#define HSTR 136     // h_s row stride in halfs (16B-aligned pad -> conflict-free b128)

typedef _Float16 half8  __attribute__((ext_vector_type(8)));
typedef float    floatx4 __attribute__((ext_vector_type(4)));

__device__ __forceinline__ float fast_exp2(float x) { return __builtin_amdgcn_exp2f(x); }
__device__ __forceinline__ float fast_rcp(float x)  { return __builtin_amdgcn_rcpf(x); }
__device__ __forceinline__ float sigmoid_f(float x) {
    return fast_rcp(1.0f + fast_exp2(-1.4426950408889634f * x));
}
__device__ __forceinline__ float tanh_f(float x) {
    return fmaf(-2.0f, fast_rcp(fast_exp2(2.8853900817779268f * x) + 1.0f), 1.0f);
}

// scale folded into q~ and cb: tanh(S/sqrt(128)) = 1 - 2/(exp2(QSCALE*S)+1)
#define QSCALE 0.2550348805576823f   // 2*log2(e)/sqrt(128)

// ---------------------------------------------------------------------------
// Kernel 1: xnorm[t,n]; apre in PERMUTED per-lane layout for k_lstm:
//   apre_p[t*512 + w*128 + l15*8 + g*2 + q] = b_ih[j]+b_hh[j]+act[t]·W_ih[j,1:]
//   where j = 128g + 32w + 16q + l15
// ---------------------------------------------------------------------------
__global__ void k_pre(const float* __restrict__ obs, const float* __restrict__ act,
                      const float* __restrict__ shift, const float* __restrict__ scale,
                      const float* __restrict__ W_ih, const float* __restrict__ b_ih,
                      const float* __restrict__ b_hh,
                      float* __restrict__ xnorm, float* __restrict__ apre_p) {
    int t = blockIdx.x;
    int tid = threadIdx.x;
    __shared__ float a_s[ACT];
    if (tid < ACT) a_s[tid] = act[t * ACT + tid];
    __syncthreads();
    for (int n = tid; n < OBS; n += 256) {
        xnorm[t * OBS + n] = (obs[t * OBS + n] - shift[n]) / (scale[n] + 1e-8f);
    }
    for (int j = tid; j < GATES; j += 256) {
        float acc = b_ih[j] + b_hh[j];
        const float* wr = W_ih + j * 33 + 1;
#pragma unroll
        for (int u = 0; u < ACT; ++u) acc = fmaf(a_s[u], wr[u], acc);
        int g = j >> 7, rem = j & 127;
        int w = rem >> 5, q = (rem >> 4) & 1, l = j & 15;
        apre_p[t * GATES + w * 128 + l * 8 + g * 2 + q] = acc;
    }
}

// ---------------------------------------------------------------------------
// Kernel 2: q~[m] = QSCALE * Wk^T (Wq pe_m + bq)  (fp16), cb[m] = QSCALE * q·bk
// ---------------------------------------------------------------------------
__global__ void k_qproj(const float* __restrict__ pe, const float* __restrict__ Wq,
                        const float* __restrict__ bq, const float* __restrict__ Wk,
                        const float* __restrict__ bk,
                        _Float16* __restrict__ qh, float* __restrict__ cb) {
    int m = blockIdx.x;
    int d = threadIdx.x;  // 0..127
    __shared__ float pe_s[PED];
    __shared__ float q_s[PED];
    __shared__ float red_s[2];
    pe_s[d] = pe[m * PED + d];
    __syncthreads();
    const float* wr = Wq + d * PED;
    float a = bq[d];
#pragma unroll 8
    for (int p = 0; p < PED; ++p) a = fmaf(pe_s[p], wr[p], a);
    q_s[d] = a;
    float pb = a * bk[d];
#pragma unroll
    for (int off = 32; off; off >>= 1) pb += __shfl_xor(pb, off, 64);
    if ((d & 63) == 0) red_s[d >> 6] = pb;
    __syncthreads();
    float acc = 0.f;
#pragma unroll 8
    for (int p = 0; p < PED; ++p) acc = fmaf(q_s[p], Wk[p * PED + d], acc);
    qh[m * PED + d] = (_Float16)(acc * QSCALE);
    if (d == 0) cb[m] = (red_s[0] + red_s[1]) * QSCALE;
}

// ---------------------------------------------------------------------------
// Kernel 3: LSTM scan via MFMA. 32 blocks x 256 threads, 16 obs-rows/block.
// W_hh stationary as B-fragments (128 VGPR/lane); h cycles through LDS as
// A-fragments (4 ds_read_b128/thread/step). Wave w owns gate columns
// {128g+32w+16q+l15} so all 4 gate types of a cell live in ONE lane's accs ->
// in-register cell update, no gate exchange. 1 barrier/step (dbuf h_s).
// Writes h (fp16) to H16[t][n][p].
// ---------------------------------------------------------------------------
__global__ __launch_bounds__(256, 1)
void k_lstm(const float* __restrict__ xnorm, const float* __restrict__ apre_p,
            const float* __restrict__ W_ih, const float* __restrict__ W_hh,
            _Float16* __restrict__ H16) {
    const int tid = threadIdx.x;
    const int lane = tid & 63, wv = tid >> 6;
    const int l15 = lane & 15, quad = lane >> 4;
    const int n0 = blockIdx.x * 16;

    // ---- stationary B-fragments: B[n=col l15][k=c*32+quad*8+j] = W_hh[col][k]
    half8 bfr[4][2][4];
#pragma unroll
    for (int g = 0; g < 4; ++g)
#pragma unroll
        for (int q = 0; q < 2; ++q) {
            const int col = 128 * g + 32 * wv + 16 * q + l15;
            const float* wrow = W_hh + (size_t)col * PED;
#pragma unroll
            for (int c = 0; c < 4; ++c) {
                const int k0 = c * 32 + quad * 8;
                float4 f0 = *(const float4*)(wrow + k0);
                float4 f1 = *(const float4*)(wrow + k0 + 4);
                bfr[g][q][c] = (half8){(_Float16)f0.x, (_Float16)f0.y, (_Float16)f0.z, (_Float16)f0.w,
                                       (_Float16)f1.x, (_Float16)f1.y, (_Float16)f1.z, (_Float16)f1.w};
            }
        }
    float wih0[4][2];
#pragma unroll
    for (int g = 0; g < 4; ++g)
#pragma unroll
        for (int q = 0; q < 2; ++q)
            wih0[g][q] = W_ih[(size_t)(128 * g + 32 * wv + 16 * q + l15) * 33];

    __shared__ _Float16 h_s[2][16 * HSTR];
    __shared__ float x_s[T_STEPS * 16];

    for (int idx = tid; idx < T_STEPS * 16; idx += 256) {
        int t = idx >> 4, r = idx & 15;
        x_s[idx] = xnorm[t * OBS + n0 + r];
    }
    for (int idx = tid; idx < 2 * 16 * HSTR; idx += 256)
        ((_Float16*)h_s)[idx] = (_Float16)0.f;

    float c_st[2][4];
#pragma unroll
    for (int q = 0; q < 2; ++q)
#pragma unroll
        for (int r = 0; r < 4; ++r) c_st[q][r] = 0.f;

    const float* apl = apre_p + wv * 128 + l15 * 8;
    float4 apA = *(const float4*)(apl);
    float4 apB = *(const float4*)(apl + 4);
    __syncthreads();

    int buf = 0;
    for (int t = 0; t < T_STEPS; ++t) {
        // ---- A-fragments: A[m=l15][k] from h_s
        half8 af[4];
        const _Float16* hb = h_s[buf] + l15 * HSTR + quad * 8;
#pragma unroll
        for (int c = 0; c < 4; ++c) af[c] = *(const half8*)(hb + c * 32);

        // ---- gates via MFMA (8 independent chains of 4)
        floatx4 acc[4][2];
#pragma unroll
        for (int g = 0; g < 4; ++g)
#pragma unroll
            for (int q = 0; q < 2; ++q) {
                acc[g][q] = (floatx4){0.f, 0.f, 0.f, 0.f};
#pragma unroll
                for (int c = 0; c < 4; ++c)
                    acc[g][q] = __builtin_amdgcn_mfma_f32_16x16x32_f16(
                        af[c], bfr[g][q][c], acc[g][q], 0, 0, 0);
            }

        // ---- prefetch apre for t+1 (off critical path)
        const int tn = (t + 1 < T_STEPS) ? t + 1 : t;
        float4 apA_n = *(const float4*)(apl + tn * GATES);
        float4 apB_n = *(const float4*)(apl + tn * GATES + 4);

        float4 x4 = *(const float4*)(x_s + t * 16 + quad * 4);
        float ap_arr[8] = {apA.x, apA.y, apA.z, apA.w, apB.x, apB.y, apB.z, apB.w};
        float xr[4] = {x4.x, x4.y, x4.z, x4.w};
        _Float16 hvals[2][4];

        // ---- cell update: 8 cells (q,r) fully in-lane
#pragma unroll
        for (int q = 0; q < 2; ++q)
#pragma unroll
            for (int r = 0; r < 4; ++r) {
                float gi = fmaf(xr[r], wih0[0][q], acc[0][q][r] + ap_arr[0 + q]);
                float gf = fmaf(xr[r], wih0[1][q], acc[1][q][r] + ap_arr[2 + q]);
                float gg = fmaf(xr[r], wih0[2][q], acc[2][q][r] + ap_arr[4 + q]);
                float go = fmaf(xr[r], wih0[3][q], acc[3][q][r] + ap_arr[6 + q]);
                float cn = sigmoid_f(gf) * c_st[q][r] + sigmoid_f(gi) * tanh_f(gg);
                c_st[q][r] = cn;
                hvals[q][r] = (_Float16)(sigmoid_f(go) * tanh_f(cn));
            }

        // ---- write h to next LDS buffer + global H16
#pragma unroll
        for (int q = 0; q < 2; ++q)
#pragma unroll
            for (int r = 0; r < 4; ++r) {
                const int row = quad * 4 + r;
                const int p = 32 * wv + 16 * q + l15;
                h_s[buf ^ 1][row * HSTR + p] = hvals[q][r];
                H16[(size_t)t * (OBS * MSG) + (size_t)(n0 + row) * MSG + p] = hvals[q][r];
            }
        apA = apA_n; apB = apB_n;
        buf ^= 1;
        __syncthreads();
    }
}

// ---------------------------------------------------------------------------
// Kernel 4: attention via fp16 MFMA, S = q~·h + cb (cb folded into acc init).
//   w = 1 - 2/(exp2(S')+1);  out[t,m] = tanh(sum_n w*s[t,n])
// grid: T*4 blocks x 256 threads; K-chunk prefetched into registers.
// ---------------------------------------------------------------------------
__global__ __launch_bounds__(256, 2)
void k_attn(const _Float16* __restrict__ qh, const float* __restrict__ cb,
            const _Float16* __restrict__ H16, const float* __restrict__ xnorm,
            float* __restrict__ outp) {
    const int t = blockIdx.x >> 2;
    const int mq = blockIdx.x & 3;
    const int tid = threadIdx.x;
    const int lane = tid & 63, wave = tid >> 6;
    const int l15 = lane & 15, quad = lane >> 4;
    const int m0 = mq * 256 + wave * 64;

    half8 afrag[4][4];
    floatx4 cbv[4];
#pragma unroll
    for (int mt = 0; mt < 4; ++mt) {
        const half8* qrow = (const half8*)(qh + (size_t)(m0 + mt * 16 + l15) * PED);
#pragma unroll
        for (int c = 0; c < 4; ++c) afrag[mt][c] = qrow[c * 4 + quad];
        cbv[mt] = *(const floatx4*)(cb + m0 + mt * 16 + quad * 4);
    }

    __shared__ half8 kbuf[64 * 16];   // 64 rows x 128 halfs = 16 KB
    __shared__ float s_s[64];

    float outacc[16];
#pragma unroll
    for (int i = 0; i < 16; ++i) outacc[i] = 0.f;

    const half8* Ht = (const half8*)(H16 + (size_t)t * (OBS * MSG));
    half8 pf[4];
    float sf = 0.f;
#pragma unroll
    for (int i = 0; i < 4; ++i) pf[i] = Ht[i * 256 + tid];
    if (tid < 64) sf = xnorm[t * OBS + tid];

    for (int ch = 0; ch < 8; ++ch) {
        __syncthreads();
#pragma unroll
        for (int i = 0; i < 4; ++i) kbuf[i * 256 + tid] = pf[i];
        if (tid < 64) s_s[tid] = sf;
        __syncthreads();
        if (ch < 7) {
            const half8* Hn = Ht + (ch + 1) * 1024;
#pragma unroll
            for (int i = 0; i < 4; ++i) pf[i] = Hn[i * 256 + tid];
            if (tid < 64) sf = xnorm[t * OBS + (ch + 1) * 64 + tid];
        }

#pragma unroll
        for (int nt = 0; nt < 4; ++nt) {
            half8 bfrag[4];
#pragma unroll
            for (int c = 0; c < 4; ++c)
                bfrag[c] = kbuf[(nt * 16 + l15) * 16 + c * 4 + quad];

            floatx4 acc[4];
#pragma unroll
            for (int mt = 0; mt < 4; ++mt) {
                acc[mt] = cbv[mt];
#pragma unroll
                for (int c = 0; c < 4; ++c)
                    acc[mt] = __builtin_amdgcn_mfma_f32_16x16x32_f16(
                        afrag[mt][c], bfrag[c], acc[mt], 0, 0, 0);
            }

            const float sv = s_s[nt * 16 + l15];
#pragma unroll
            for (int mt = 0; mt < 4; ++mt)
#pragma unroll
                for (int r = 0; r < 4; ++r) {
                    float e = fast_exp2(acc[mt][r]);
                    float w = fmaf(-2.0f, fast_rcp(e + 1.0f), 1.0f);
                    outacc[mt * 4 + r] = fmaf(w, sv, outacc[mt * 4 + r]);
                }
        }
    }

#pragma unroll
    for (int i = 0; i < 16; ++i) {
        float v = outacc[i];
        v += __shfl_xor(v, 1, 16);
        v += __shfl_xor(v, 2, 16);
        v += __shfl_xor(v, 4, 16);
        v += __shfl_xor(v, 8, 16);
        outacc[i] = v;
    }
    if (l15 == 0) {
        const int mbase = m0 + quad * 4;
#pragma unroll
        for (int mt = 0; mt < 4; ++mt)
#pragma unroll
            for (int r = 0; r < 4; ++r)
                outp[(size_t)t * HID + mbase + mt * 16 + r] = tanh_f(outacc[mt * 4 + r]);
    }
}

// ---------------------------------------------------------------------------
extern "C" void kernel_launch(void* const* d_in, const int* in_sizes, int n_in,
                              void* d_out, int out_size, void* d_ws, size_t ws_size,
                              hipStream_t stream) {
    const float* obs      = (const float*)d_in[0];   // (256,512)
    const float* prev_act = (const float*)d_in[1];   // (256,32)
    const float* in_shift = (const float*)d_in[2];   // (512,)
    const float* in_scale = (const float*)d_in[3];   // (512,)
    const float* pos_emb  = (const float*)d_in[4];   // (1024,128)
    const float* W_ih     = (const float*)d_in[5];   // (512,33)
    const float* b_ih     = (const float*)d_in[6];   // (512,)
    const float* b_hh     = (const float*)d_in[8];   // (512,)
    const float* W_hh     = (const float*)d_in[7];   // (512,128)
    const float* Wq       = (const float*)d_in[9];   // (128,128)
    const float* bq       = (const float*)d_in[10];  // (128,)
    const float* Wk       = (const float*)d_in[11];  // (128,128)
    const float* bk       = (const float*)d_in[12];  // (128,)
    float* outp = (float*)d_out;                     // (256,1024)

    // workspace layout (float offsets):
    //   xnorm:  0        (131072 f)
    //   apre_p: 131072   (131072 f)
    //   qh:     262144   (131072 halfs)
    //   cb:     327680   (1024 f)
    //   H16:    328704   (16777216 halfs)
    float* ws = (float*)d_ws;
    float* xnorm  = ws;
    float* apre_p = ws + 131072;
    _Float16* qh  = (_Float16*)(ws + 262144);
    float* cbuf   = ws + 327680;
    _Float16* H16 = (_Float16*)(ws + 328704);

    k_pre<<<T_STEPS, 256, 0, stream>>>(obs, prev_act, in_shift, in_scale,
                                       W_ih, b_ih, b_hh, xnorm, apre_p);
    k_qproj<<<HID, 128, 0, stream>>>(pos_emb, Wq, bq, Wk, bk, qh, cbuf);
    k_lstm<<<32, 256, 0, stream>>>(xnorm, apre_p, W_ih, W_hh, H16);
    k_attn<<<T_STEPS * 4, 256, 0, stream>>>(qh, cbuf, H16, xnorm, outp);
}

// Round 4
// 377.364 us; speedup vs baseline: 4.8055x; 1.1319x over previous
//
#include <hip/hip_runtime.h>
#include <hip/hip_fp16.h>

#define T_STEPS 256
#define OBS 512      // obs dim = number of independent per-row LSTMs
#define ACT 32
#define HID 1024     // output rows (hidden_dim)
#define PED 128      // pos_em_dim = LSTM hidden size
#define MSG 128      // msg_dim
#define GATES 512    // 4*PED
#define HSTR 136     // h_s row stride in halfs (272B -> 2-way max on b128 = free)
#define KSTR 17      // kbuf row stride in half8 units (272B)

typedef _Float16 half8  __attribute__((ext_vector_type(8)));
typedef float    floatx4 __attribute__((ext_vector_type(4)));

__device__ __forceinline__ float fast_exp2(float x) { return __builtin_amdgcn_exp2f(x); }
__device__ __forceinline__ float fast_rcp(float x)  { return __builtin_amdgcn_rcpf(x); }
__device__ __forceinline__ float sigmoid_f(float x) {
    return fast_rcp(1.0f + fast_exp2(-1.4426950408889634f * x));
}
__device__ __forceinline__ float tanh_f(float x) {
    return fmaf(-2.0f, fast_rcp(fast_exp2(2.8853900817779268f * x) + 1.0f), 1.0f);
}

// scale folded into q~ and cb: tanh(S/sqrt(128)) = 1 - 2/(exp2(QSCALE*S)+1)
#define QSCALE 0.2550348805576823f   // 2*log2(e)/sqrt(128)

// ---------------------------------------------------------------------------
// Kernel 1: xnorm[t,n]; apre in [t][p][g] layout:
//   apre_p[t*512 + p*4 + g] = b_ih[j]+b_hh[j]+act[t]·W_ih[j,1:],  j = 128g+p
// ---------------------------------------------------------------------------
__global__ void k_pre(const float* __restrict__ obs, const float* __restrict__ act,
                      const float* __restrict__ shift, const float* __restrict__ scale,
                      const float* __restrict__ W_ih, const float* __restrict__ b_ih,
                      const float* __restrict__ b_hh,
                      float* __restrict__ xnorm, float* __restrict__ apre_p) {
    int t = blockIdx.x;
    int tid = threadIdx.x;
    __shared__ float a_s[ACT];
    if (tid < ACT) a_s[tid] = act[t * ACT + tid];
    __syncthreads();
    for (int n = tid; n < OBS; n += 256) {
        xnorm[t * OBS + n] = (obs[t * OBS + n] - shift[n]) / (scale[n] + 1e-8f);
    }
    for (int j = tid; j < GATES; j += 256) {
        float acc = b_ih[j] + b_hh[j];
        const float* wr = W_ih + j * 33 + 1;
#pragma unroll
        for (int u = 0; u < ACT; ++u) acc = fmaf(a_s[u], wr[u], acc);
        int g = j >> 7, p = j & 127;
        apre_p[t * GATES + p * 4 + g] = acc;
    }
}

// ---------------------------------------------------------------------------
// Kernel 2: q~[m] = QSCALE * Wk^T (Wq pe_m + bq)  (fp16), cb[m] = QSCALE * q·bk
// ---------------------------------------------------------------------------
__global__ void k_qproj(const float* __restrict__ pe, const float* __restrict__ Wq,
                        const float* __restrict__ bq, const float* __restrict__ Wk,
                        const float* __restrict__ bk,
                        _Float16* __restrict__ qh, float* __restrict__ cb) {
    int m = blockIdx.x;
    int d = threadIdx.x;  // 0..127
    __shared__ float pe_s[PED];
    __shared__ float q_s[PED];
    __shared__ float red_s[2];
    pe_s[d] = pe[m * PED + d];
    __syncthreads();
    const float* wr = Wq + d * PED;
    float a = bq[d];
#pragma unroll 8
    for (int p = 0; p < PED; ++p) a = fmaf(pe_s[p], wr[p], a);
    q_s[d] = a;
    float pb = a * bk[d];
#pragma unroll
    for (int off = 32; off; off >>= 1) pb += __shfl_xor(pb, off, 64);
    if ((d & 63) == 0) red_s[d >> 6] = pb;
    __syncthreads();
    float acc = 0.f;
#pragma unroll 8
    for (int p = 0; p < PED; ++p) acc = fmaf(q_s[p], Wk[p * PED + d], acc);
    qh[m * PED + d] = (_Float16)(acc * QSCALE);
    if (d == 0) cb[m] = (red_s[0] + red_s[1]) * QSCALE;
}

// ---------------------------------------------------------------------------
// Kernel 3: LSTM scan via MFMA. 32 blocks x 512 threads (8 waves = 2/SIMD),
// 16 obs-rows/block. Wave w owns units p in [16w,16w+16): 4 gate chains of
// 4 MFMAs (16 mfma/wave/step). All 4 gates of cell (row,p) land in ONE lane
// -> in-register cell update (4 cells/lane). Two waves per SIMD let the
// hardware overlap MFMA-pipe and trans-pipe phases across waves.
// ---------------------------------------------------------------------------
__global__ __launch_bounds__(512, 2)
void k_lstm(const float* __restrict__ xnorm, const float* __restrict__ apre_p,
            const float* __restrict__ W_ih, const float* __restrict__ W_hh,
            _Float16* __restrict__ H16) {
    const int tid = threadIdx.x;
    const int lane = tid & 63, wv = tid >> 6;     // 8 waves
    const int l15 = lane & 15, quad = lane >> 4;
    const int n0 = blockIdx.x * 16;
    const int p = 16 * wv + l15;                  // h-unit this lane owns

    // ---- stationary B-fragments: B[n=col][k] = W_hh[col][k], col = 128g+p
    half8 bfr[4][4];
    float wih0[4];
#pragma unroll
    for (int g = 0; g < 4; ++g) {
        const int col = 128 * g + p;
        const float* wrow = W_hh + (size_t)col * PED;
#pragma unroll
        for (int c = 0; c < 4; ++c) {
            const int k0 = c * 32 + quad * 8;
            float4 f0 = *(const float4*)(wrow + k0);
            float4 f1 = *(const float4*)(wrow + k0 + 4);
            bfr[g][c] = (half8){(_Float16)f0.x, (_Float16)f0.y, (_Float16)f0.z, (_Float16)f0.w,
                                (_Float16)f1.x, (_Float16)f1.y, (_Float16)f1.z, (_Float16)f1.w};
        }
        wih0[g] = W_ih[(size_t)col * 33];
    }

    __shared__ _Float16 h_s[2][16 * HSTR];
    __shared__ float x_s[T_STEPS * 16];

    for (int idx = tid; idx < T_STEPS * 16; idx += 512) {
        x_s[idx] = xnorm[(idx >> 4) * OBS + n0 + (idx & 15)];
    }
    for (int idx = tid; idx < 2 * 16 * HSTR; idx += 512)
        ((_Float16*)h_s)[idx] = (_Float16)0.f;

    float c_st[4] = {0.f, 0.f, 0.f, 0.f};

    const float* apl = apre_p + p * 4;
    float4 ap = *(const float4*)(apl);            // t=0: (gi,gf,gg,go) pre-add
    __syncthreads();

    int buf = 0;
    for (int t = 0; t < T_STEPS; ++t) {
        // ---- A-fragments: A[m=l15][k] from h_s (b128, conflict-free)
        half8 af[4];
        const _Float16* hb = h_s[buf] + l15 * HSTR + quad * 8;
#pragma unroll
        for (int c = 0; c < 4; ++c) af[c] = *(const half8*)(hb + c * 32);

        // ---- gates via MFMA: 4 independent chains of 4
        floatx4 acc[4];
#pragma unroll
        for (int g = 0; g < 4; ++g) {
            acc[g] = (floatx4){0.f, 0.f, 0.f, 0.f};
#pragma unroll
            for (int c = 0; c < 4; ++c)
                acc[g] = __builtin_amdgcn_mfma_f32_16x16x32_f16(
                    af[c], bfr[g][c], acc[g], 0, 0, 0);
        }

        // ---- prefetch apre for t+1 (off critical path)
        const int tn = (t + 1 < T_STEPS) ? t + 1 : t;
        float4 ap_n = *(const float4*)(apl + tn * GATES);

        float4 x4 = *(const float4*)(x_s + t * 16 + quad * 4);
        float xr[4] = {x4.x, x4.y, x4.z, x4.w};
        _Float16 hvals[4];

        // ---- cell update: 4 cells (rows quad*4+r, unit p), fully in-lane
#pragma unroll
        for (int r = 0; r < 4; ++r) {
            float gi = fmaf(xr[r], wih0[0], acc[0][r] + ap.x);
            float gf = fmaf(xr[r], wih0[1], acc[1][r] + ap.y);
            float gg = fmaf(xr[r], wih0[2], acc[2][r] + ap.z);
            float go = fmaf(xr[r], wih0[3], acc[3][r] + ap.w);
            float cn = sigmoid_f(gf) * c_st[r] + sigmoid_f(gi) * tanh_f(gg);
            c_st[r] = cn;
            hvals[r] = (_Float16)(sigmoid_f(go) * tanh_f(cn));
        }

        // ---- write h to next LDS buffer + global H16
#pragma unroll
        for (int r = 0; r < 4; ++r) {
            const int row = quad * 4 + r;
            h_s[buf ^ 1][row * HSTR + p] = hvals[r];
            H16[(size_t)t * (OBS * MSG) + (size_t)(n0 + row) * MSG + p] = hvals[r];
        }
        ap = ap_n;
        buf ^= 1;
        __syncthreads();
    }
}

// ---------------------------------------------------------------------------
// Kernel 4: attention via fp16 MFMA, S = q~·h + cb (cb folded into acc init).
//   w = 1 - 2/(exp2(S')+1);  out[t,m] = tanh(sum_n w*s[t,n])
// grid: T*4 blocks x 256 threads; K-chunk prefetched into registers.
// kbuf rows padded to 17 half8 (272B) -> B-frag b128 reads conflict-free.
// ---------------------------------------------------------------------------
__global__ __launch_bounds__(256, 2)
void k_attn(const _Float16* __restrict__ qh, const float* __restrict__ cb,
            const _Float16* __restrict__ H16, const float* __restrict__ xnorm,
            float* __restrict__ outp) {
    const int t = blockIdx.x >> 2;
    const int mq = blockIdx.x & 3;
    const int tid = threadIdx.x;
    const int lane = tid & 63, wave = tid >> 6;
    const int l15 = lane & 15, quad = lane >> 4;
    const int m0 = mq * 256 + wave * 64;

    half8 afrag[4][4];
    floatx4 cbv[4];
#pragma unroll
    for (int mt = 0; mt < 4; ++mt) {
        const half8* qrow = (const half8*)(qh + (size_t)(m0 + mt * 16 + l15) * PED);
#pragma unroll
        for (int c = 0; c < 4; ++c) afrag[mt][c] = qrow[c * 4 + quad];
        cbv[mt] = *(const floatx4*)(cb + m0 + mt * 16 + quad * 4);
    }

    __shared__ half8 kbuf[64 * KSTR];   // 64 rows x 17 half8 (padded)
    __shared__ float s_s[64];

    float outacc[16];
#pragma unroll
    for (int i = 0; i < 16; ++i) outacc[i] = 0.f;

    const half8* Ht = (const half8*)(H16 + (size_t)t * (OBS * MSG));
    half8 pf[4];
    float sf = 0.f;
#pragma unroll
    for (int i = 0; i < 4; ++i) pf[i] = Ht[i * 256 + tid];
    if (tid < 64) sf = xnorm[t * OBS + tid];

    for (int ch = 0; ch < 8; ++ch) {
        __syncthreads();
#pragma unroll
        for (int i = 0; i < 4; ++i) {
            int f = i * 256 + tid;
            kbuf[(f >> 4) * KSTR + (f & 15)] = pf[i];
        }
        if (tid < 64) s_s[tid] = sf;
        __syncthreads();
        if (ch < 7) {
            const half8* Hn = Ht + (ch + 1) * 1024;
#pragma unroll
            for (int i = 0; i < 4; ++i) pf[i] = Hn[i * 256 + tid];
            if (tid < 64) sf = xnorm[t * OBS + (ch + 1) * 64 + tid];
        }

#pragma unroll
        for (int nt = 0; nt < 4; ++nt) {
            half8 bfrag[4];
#pragma unroll
            for (int c = 0; c < 4; ++c)
                bfrag[c] = kbuf[(nt * 16 + l15) * KSTR + c * 4 + quad];

            floatx4 acc[4];
#pragma unroll
            for (int mt = 0; mt < 4; ++mt) {
                acc[mt] = cbv[mt];
#pragma unroll
                for (int c = 0; c < 4; ++c)
                    acc[mt] = __builtin_amdgcn_mfma_f32_16x16x32_f16(
                        afrag[mt][c], bfrag[c], acc[mt], 0, 0, 0);
            }

            const float sv = s_s[nt * 16 + l15];
#pragma unroll
            for (int mt = 0; mt < 4; ++mt)
#pragma unroll
                for (int r = 0; r < 4; ++r) {
                    float e = fast_exp2(acc[mt][r]);
                    float w = fmaf(-2.0f, fast_rcp(e + 1.0f), 1.0f);
                    outacc[mt * 4 + r] = fmaf(w, sv, outacc[mt * 4 + r]);
                }
        }
    }

#pragma unroll
    for (int i = 0; i < 16; ++i) {
        float v = outacc[i];
        v += __shfl_xor(v, 1, 16);
        v += __shfl_xor(v, 2, 16);
        v += __shfl_xor(v, 4, 16);
        v += __shfl_xor(v, 8, 16);
        outacc[i] = v;
    }
    if (l15 == 0) {
        const int mbase = m0 + quad * 4;
#pragma unroll
        for (int mt = 0; mt < 4; ++mt)
#pragma unroll
            for (int r = 0; r < 4; ++r)
                outp[(size_t)t * HID + mbase + mt * 16 + r] = tanh_f(outacc[mt * 4 + r]);
    }
}

// ---------------------------------------------------------------------------
extern "C" void kernel_launch(void* const* d_in, const int* in_sizes, int n_in,
                              void* d_out, int out_size, void* d_ws, size_t ws_size,
                              hipStream_t stream) {
    const float* obs      = (const float*)d_in[0];   // (256,512)
    const float* prev_act = (const float*)d_in[1];   // (256,32)
    const float* in_shift = (const float*)d_in[2];   // (512,)
    const float* in_scale = (const float*)d_in[3];   // (512,)
    const float* pos_emb  = (const float*)d_in[4];   // (1024,128)
    const float* W_ih     = (const float*)d_in[5];   // (512,33)
    const float* b_ih     = (const float*)d_in[6];   // (512,)
    const float* W_hh     = (const float*)d_in[7];   // (512,128)
    const float* b_hh     = (const float*)d_in[8];   // (512,)
    const float* Wq       = (const float*)d_in[9];   // (128,128)
    const float* bq       = (const float*)d_in[10];  // (128,)
    const float* Wk       = (const float*)d_in[11];  // (128,128)
    const float* bk       = (const float*)d_in[12];  // (128,)
    float* outp = (float*)d_out;                     // (256,1024)

    // workspace layout (float offsets):
    //   xnorm:  0        (131072 f)
    //   apre_p: 131072   (131072 f)
    //   qh:     262144   (131072 halfs)
    //   cb:     327680   (1024 f)
    //   H16:    328704   (16777216 halfs)
    float* ws = (float*)d_ws;
    float* xnorm  = ws;
    float* apre_p = ws + 131072;
    _Float16* qh  = (_Float16*)(ws + 262144);
    float* cbuf   = ws + 327680;
    _Float16* H16 = (_Float16*)(ws + 328704);

    k_pre<<<T_STEPS, 256, 0, stream>>>(obs, prev_act, in_shift, in_scale,
                                       W_ih, b_ih, b_hh, xnorm, apre_p);
    k_qproj<<<HID, 128, 0, stream>>>(pos_emb, Wq, bq, Wk, bk, qh, cbuf);
    k_lstm<<<32, 512, 0, stream>>>(xnorm, apre_p, W_ih, W_hh, H16);
    k_attn<<<T_STEPS * 4, 256, 0, stream>>>(qh, cbuf, H16, xnorm, outp);
}